// Round 1
// baseline (1735.108 us; speedup 1.0000x reference)
//
#include <hip/hip_runtime.h>
#include <cstdint>
#include <cstddef>

// ---------------- constants ----------------
#define Bq 8
#define Sq 2048
#define Dq 4096
#define Oq 4096
#define Eq 8
#define Rq 16
#define IMG_START 34
#define IMG_LEN 576
#define SCALING 2.0f

#define M_TOT (Bq * Sq)          // 16384
#define FINAL_N ((size_t)M_TOT * Oq)          // 67108864
#define ROUT_OFF FINAL_N                       // routing at 67108864
#define EC_OFF (FINAL_N + (size_t)Bq * IMG_LEN * Eq)  // 67145728

typedef short bf16x8 __attribute__((ext_vector_type(8)));
typedef float f32x4 __attribute__((ext_vector_type(4)));

// ---------------- helpers ----------------
__device__ __forceinline__ unsigned short f2bf(float f) {
    unsigned int u = __float_as_uint(f);
    unsigned int lsb = (u >> 16) & 1u;
    u += 0x7fffu + lsb;           // round-to-nearest-even
    return (unsigned short)(u >> 16);
}

__device__ __forceinline__ void gload16(const void* g, void* l) {
    __builtin_amdgcn_global_load_lds(
        (const __attribute__((address_space(1))) void*)g,
        (__attribute__((address_space(3))) void*)l, 16, 0, 0);
}

// ---------------- fp32 -> bf16 convert ----------------
__global__ __launch_bounds__(256) void cvt_kernel(const float* __restrict__ in,
                                                  unsigned short* __restrict__ out,
                                                  long n4) {
    long i = (long)blockIdx.x * blockDim.x + threadIdx.x;
    long stride = (long)gridDim.x * blockDim.x;
    typedef unsigned short us4 __attribute__((ext_vector_type(4)));
    for (long v = i; v < n4; v += stride) {
        float4 f = ((const float4*)in)[v];
        us4 o;
        o.x = f2bf(f.x); o.y = f2bf(f.y); o.z = f2bf(f.z); o.w = f2bf(f.w);
        ((us4*)out)[v] = o;
    }
}

// ---------------- bf16 GEMM, B^T layout (m97 structure) ----------------
// C[m][n] = sum_k A[m][k] * Bt[n][k]  (+ bias[n])
#define BM 128
#define BN 128
#define BK 64

__global__ __launch_bounds__(256, 3) void gemm_bt(
    const unsigned short* __restrict__ A,   // [M][K] bf16
    const unsigned short* __restrict__ Bt,  // [N][K] bf16
    const float* __restrict__ bias,         // [N]
    float* __restrict__ C) {                // [M][N] fp32
    const int Mn = M_TOT, Nn = Oq, Kn = Dq;

    __shared__ __align__(16) unsigned short As[BM * BK];
    __shared__ __align__(16) unsigned short Bs[BN * BK];

    int tid = threadIdx.x;
    int lane = tid & 63;
    int wid = tid >> 6;

    // XCD-aware swizzle (nwg = 4096, divisible by 8)
    int nbn = Nn / BN;                       // 32
    int nwg = (Mn / BM) * nbn;               // 4096
    int cpx = nwg >> 3;
    int bid = blockIdx.x;
    int swz = (bid & 7) * cpx + (bid >> 3);
    int tm = swz / nbn, tn = swz % nbn;

    int wr = wid >> 1, wc = wid & 1;         // 2x2 wave grid, each wave 64x64
    int lr = lane & 15;                      // frag row (A) / col (B,D)
    int lk = (lane >> 4) * 8;                // frag k-offset

    f32x4 acc[4][4] = {};

    const size_t arow0 = (size_t)tm * BM;
    const size_t brow0 = (size_t)tn * BN;

    for (int kt = 0; kt < Kn; kt += BK) {
        // ---- stage A tile: 128x64 bf16 via 4 x (256 lanes x 16B) ----
#pragma unroll
        for (int i = 0; i < 4; ++i) {
            int chunk = i * 256 + tid;
            int row = chunk >> 3, c8 = chunk & 7;
            gload16(A + (arow0 + row) * Kn + kt + c8 * 8,
                    &As[(size_t)(i * 256 + (wid << 6)) * 8]);
        }
#pragma unroll
        for (int i = 0; i < 4; ++i) {
            int chunk = i * 256 + tid;
            int row = chunk >> 3, c8 = chunk & 7;
            gload16(Bt + (brow0 + row) * Kn + kt + c8 * 8,
                    &Bs[(size_t)(i * 256 + (wid << 6)) * 8]);
        }
        __syncthreads();

#pragma unroll
        for (int kk = 0; kk < BK; kk += 32) {
            bf16x8 af[4], bf[4];
#pragma unroll
            for (int mi = 0; mi < 4; ++mi)
                af[mi] = *(const bf16x8*)&As[(wr * 64 + mi * 16 + lr) * BK + kk + lk];
#pragma unroll
            for (int ni = 0; ni < 4; ++ni)
                bf[ni] = *(const bf16x8*)&Bs[(wc * 64 + ni * 16 + lr) * BK + kk + lk];
#pragma unroll
            for (int mi = 0; mi < 4; ++mi)
#pragma unroll
                for (int ni = 0; ni < 4; ++ni)
                    acc[mi][ni] = __builtin_amdgcn_mfma_f32_16x16x32_bf16(
                        af[mi], bf[ni], acc[mi][ni], 0, 0, 0);
        }
        __syncthreads();
    }

    // ---- epilogue: D layout col=lane&15, row=(lane>>4)*4+reg ----
#pragma unroll
    for (int ni = 0; ni < 4; ++ni) {
        int col = tn * BN + wc * 64 + ni * 16 + lr;
        float bv = bias[col];
#pragma unroll
        for (int mi = 0; mi < 4; ++mi) {
            int row0 = tm * BM + wr * 64 + mi * 16 + ((lane >> 4) << 2);
            f32x4 v = acc[mi][ni];
#pragma unroll
            for (int r = 0; r < 4; ++r)
                C[(size_t)(row0 + r) * Nn + col] = v[r] + bv;
        }
    }
}

// ---------------- routing + LoRA (adds into C) ----------------
__global__ __launch_bounds__(256) void route_lora(
    const float* __restrict__ x,    // [B][S][D]
    const float* __restrict__ A,    // [E][R][D]
    const float* __restrict__ Bm,   // [E][O][R]
    const float* __restrict__ Wr,   // [E][D]
    const float* __restrict__ br,   // [E]
    float* __restrict__ out) {
    int token = blockIdx.x;              // 0 .. B*IMG_LEN-1
    int bb = token / IMG_LEN, si = token - bb * IMG_LEN;
    int s = IMG_START + si;
    const float* xrow = x + ((size_t)bb * Sq + s) * Dq;

    __shared__ __align__(16) float xs[Dq];
    __shared__ double lg[Eq];
    __shared__ float tv[Rq];
    __shared__ int esel;

    int tid = threadIdx.x, lane = tid & 63, wid = tid >> 6;

    for (int i = tid; i < Dq / 4; i += 256)
        ((float4*)xs)[i] = ((const float4*)xrow)[i];
    __syncthreads();

    // logits in fp64 (argmax stability vs reference)
#pragma unroll
    for (int eo = 0; eo < 2; ++eo) {
        int e = wid * 2 + eo;
        const float* wre = Wr + (size_t)e * Dq;
        double sum = 0.0;
        for (int k = lane; k < Dq; k += 64)
            sum += (double)xs[k] * (double)wre[k];
        for (int off = 32; off; off >>= 1) sum += __shfl_xor(sum, off);
        if (lane == 0) lg[e] = sum + (double)br[e];
    }
    __syncthreads();

    if (tid == 0) {
        double mx = lg[0]; int am = 0;
        for (int e = 1; e < Eq; ++e) if (lg[e] > mx) { mx = lg[e]; am = e; }
        double ex[Eq], den = 0.0;
        for (int e = 0; e < Eq; ++e) { ex[e] = exp(lg[e] - mx); den += ex[e]; }
        for (int e = 0; e < Eq; ++e) {
            float rf = (float)(ex[e] / den);
            out[ROUT_OFF + (size_t)token * Eq + e] = rf;
            float oh = (e == am) ? 1.0f : 0.0f;
            out[EC_OFF + (size_t)token * Eq + e] = (oh - rf) + rf;
        }
        esel = am;
    }
    __syncthreads();
    int e = esel;

    // t[r] = dot(x, A[e][r])
#pragma unroll
    for (int ro = 0; ro < 4; ++ro) {
        int r = wid * 4 + ro;
        const float* ar = A + ((size_t)e * Rq + r) * Dq;
        float sum = 0.0f;
        for (int k = lane; k < Dq; k += 64) sum += xs[k] * ar[k];
        for (int off = 32; off; off >>= 1) sum += __shfl_xor(sum, off);
        if (lane == 0) tv[r] = sum;
    }
    __syncthreads();

    // lora[o] = 2 * sum_r t[r] * Bm[e][o][r], RMW into out
    float* orow = out + ((size_t)bb * Sq + s) * Oq;
    for (int o = tid; o < Oq; o += 256) {
        const float4* bp = (const float4*)(Bm + ((size_t)e * Oq + o) * Rq);
        float acc = 0.0f;
#pragma unroll
        for (int j = 0; j < 4; ++j) {
            float4 bv = bp[j];
            acc += bv.x * tv[j * 4 + 0] + bv.y * tv[j * 4 + 1] +
                   bv.z * tv[j * 4 + 2] + bv.w * tv[j * 4 + 3];
        }
        orow[o] += SCALING * acc;
    }
}

// ---------------- launch ----------------
extern "C" void kernel_launch(void* const* d_in, const int* in_sizes, int n_in,
                              void* d_out, int out_size, void* d_ws, size_t ws_size,
                              hipStream_t stream) {
    const float* x  = (const float*)d_in[0];
    const float* W  = (const float*)d_in[1];
    const float* b  = (const float*)d_in[2];
    const float* A  = (const float*)d_in[3];
    const float* Bm = (const float*)d_in[4];
    const float* Wr = (const float*)d_in[5];
    const float* br = (const float*)d_in[6];
    float* out = (float*)d_out;

    unsigned short* xb = (unsigned short*)d_ws;                       // 16384*4096 bf16
    unsigned short* Wb = xb + (size_t)M_TOT * Dq;                     // 4096*4096 bf16

    cvt_kernel<<<2048, 256, 0, stream>>>(x, xb, (long)M_TOT * Dq / 4);
    cvt_kernel<<<1024, 256, 0, stream>>>(W, Wb, (long)Oq * Dq / 4);

    gemm_bt<<<(M_TOT / BM) * (Oq / BN), 256, 0, stream>>>(xb, Wb, b, out);

    route_lora<<<Bq * IMG_LEN, 256, 0, stream>>>(x, A, Bm, Wr, br, out);
}

// Round 2
// 1660.384 us; speedup vs baseline: 1.0450x; 1.0450x over previous
//
#include <hip/hip_runtime.h>
#include <cstdint>
#include <cstddef>

// ---------------- constants ----------------
#define Bq 8
#define Sq 2048
#define Dq 4096
#define Oq 4096
#define Eq 8
#define Rq 16
#define IMG_START 34
#define IMG_LEN 576
#define SCALING 2.0f

#define M_TOT (Bq * Sq)                         // 16384
#define FINAL_N ((size_t)M_TOT * Oq)            // 67108864
#define ROUT_OFF FINAL_N
#define EC_OFF (FINAL_N + (size_t)Bq * IMG_LEN * Eq)

#define NT 64                                   // K tiles of 64 (K = 4096)

typedef short bf16x8 __attribute__((ext_vector_type(8)));
typedef float f32x4 __attribute__((ext_vector_type(4)));

// ---------------- helpers ----------------
__device__ __forceinline__ unsigned short f2bf(float f) {
    unsigned int u = __float_as_uint(f);
    unsigned int lsb = (u >> 16) & 1u;
    u += 0x7fffu + lsb;           // round-to-nearest-even
    return (unsigned short)(u >> 16);
}

__device__ __forceinline__ void gload16(const void* g, void* l) {
    __builtin_amdgcn_global_load_lds(
        (const __attribute__((address_space(1))) void*)g,
        (__attribute__((address_space(3))) void*)l, 16, 0, 0);
}

// ---------------- fp32 -> bf16 convert ----------------
__global__ __launch_bounds__(256) void cvt_kernel(const float* __restrict__ in,
                                                  unsigned short* __restrict__ out,
                                                  long n4) {
    long i = (long)blockIdx.x * blockDim.x + threadIdx.x;
    long stride = (long)gridDim.x * blockDim.x;
    typedef unsigned short us4 __attribute__((ext_vector_type(4)));
    for (long v = i; v < n4; v += stride) {
        float4 f = ((const float4*)in)[v];
        us4 o;
        o.x = f2bf(f.x); o.y = f2bf(f.y); o.z = f2bf(f.z); o.w = f2bf(f.w);
        ((us4*)out)[v] = o;
    }
}

// ---------------- bf16 GEMM, 256x256 tile, 8-phase counted-vmcnt ----------------
// C[m][n] = sum_k A[m][k] * Bt[n][k] + bias[n]
// 8 waves (2M x 4N), per-wave output 128x64. LDS 128 KiB:
//   ldsA[buf][half][128 rows][64 cols] (half mh holds, per wr, rows wr*128+mh*64..+63)
//   ldsB[buf][half][128 rows][64 cols] (half nh holds, per wc, rows wc*64+nh*32..+31)
// XOR swizzle: 16B chunk slot = c ^ (row&7); staged via pre-swizzled global source.
// vmcnt(4) at end of phases 4 and 8 only (2 stages = 4 loads in flight).

__global__ __launch_bounds__(512, 2) void gemm256(
    const unsigned short* __restrict__ Ag,   // [M][K] bf16
    const unsigned short* __restrict__ Bg,   // [N][K] bf16
    const float* __restrict__ bias,          // [N]
    float* __restrict__ C) {                 // [M][N] fp32
    __shared__ __align__(16) unsigned short ldsA[2][2][8192];
    __shared__ __align__(16) unsigned short ldsB[2][2][8192];

    const int tid = threadIdx.x;
    const int lane = tid & 63, wid = tid >> 6;
    const int wr = wid >> 2, wc = wid & 3;
    const int lr = lane & 15, hi = lane >> 4, l7 = lane & 7;

    // XCD-aware swizzle: nwg = 64*16 = 1024, %8 == 0 -> simple bijective form
    int bid = blockIdx.x;
    int swz = (bid & 7) * 128 + (bid >> 3);
    int tm = swz >> 4, tn = swz & 15;
    const size_t mrow0 = (size_t)tm * 256, nrow0 = (size_t)tn * 256;

    // ---- staging constants (per-thread) ----
    // chunk q = l*512 + tid; stored row = q>>3, slot = q&7; logical chunk c = slot ^ (row&7)
    const int q0 = tid, q1 = 512 + tid;
    const int r0 = q0 >> 3, c0 = (q0 & 7) ^ (r0 & 7);
    const int r1 = q1 >> 3, c1 = (q1 & 7) ^ (r1 & 7);
    // element offsets excluding the half term (A: +mh*64 rows, B: +nh*32 rows)
    const size_t garow0 = (mrow0 + (size_t)((r0 >> 6) << 7) + (r0 & 63)) * Dq + c0 * 8;
    const size_t garow1 = (mrow0 + (size_t)((r1 >> 6) << 7) + (r1 & 63)) * Dq + c1 * 8;
    const size_t gbrow0 = (nrow0 + (size_t)((r0 >> 5) << 6) + (r0 & 31)) * Dq + c0 * 8;
    const size_t gbrow1 = (nrow0 + (size_t)((r1 >> 5) << 6) + (r1 & 31)) * Dq + c1 * 8;
    // LDS dest: wave-uniform base + lane*16B (linear; HW adds lane offset)
    const int ldst0 = (0 * 512 + (wid << 6)) * 8;   // ushort index
    const int ldst1 = (1 * 512 + (wid << 6)) * 8;

    // ---- ds_read constants ----
    const int sl0 = (hi ^ l7) * 8;          // kk=0..31 slot (ushort idx)
    const int sl1 = ((4 + hi) ^ l7) * 8;    // kk=32..63 slot
    const int arow = wr * 4096 + lr * 64;   // + mi*1024
    const int brow = wc * 2048 + lr * 64;   // + ni*1024

    f32x4 acc[8][4] = {};

#define STAGE_A(bf, mh, tile) do {                                              \
        int kt_ = ((tile) < NT ? (tile) : NT - 1) * 64;                         \
        gload16(Ag + garow0 + (size_t)(mh) * 64 * Dq + kt_, &ldsA[bf][mh][ldst0]); \
        gload16(Ag + garow1 + (size_t)(mh) * 64 * Dq + kt_, &ldsA[bf][mh][ldst1]); \
    } while (0)
#define STAGE_B(bf, nh, tile) do {                                              \
        int kt_ = ((tile) < NT ? (tile) : NT - 1) * 64;                         \
        gload16(Bg + gbrow0 + (size_t)(nh) * 32 * Dq + kt_, &ldsB[bf][nh][ldst0]); \
        gload16(Bg + gbrow1 + (size_t)(nh) * 32 * Dq + kt_, &ldsB[bf][nh][ldst1]); \
    } while (0)

#define PHASE(bf, mh, nh, STAGES, WAITC) do {                                   \
        bf16x8 a0[4], a1[4], b0[2], b1[2];                                      \
        _Pragma("unroll") for (int mi = 0; mi < 4; ++mi) {                      \
            a0[mi] = *(const bf16x8*)&ldsA[bf][mh][arow + mi * 1024 + sl0];     \
            a1[mi] = *(const bf16x8*)&ldsA[bf][mh][arow + mi * 1024 + sl1];     \
        }                                                                       \
        _Pragma("unroll") for (int ni = 0; ni < 2; ++ni) {                      \
            b0[ni] = *(const bf16x8*)&ldsB[bf][nh][brow + ni * 1024 + sl0];     \
            b1[ni] = *(const bf16x8*)&ldsB[bf][nh][brow + ni * 1024 + sl1];     \
        }                                                                       \
        STAGES                                                                  \
        asm volatile("s_barrier" ::: "memory");                                 \
        asm volatile("s_waitcnt lgkmcnt(0)" ::: "memory");                      \
        __builtin_amdgcn_sched_barrier(0);                                      \
        __builtin_amdgcn_s_setprio(1);                                          \
        _Pragma("unroll") for (int mi = 0; mi < 4; ++mi)                        \
            _Pragma("unroll") for (int ni = 0; ni < 2; ++ni) {                  \
                acc[(mh) * 4 + mi][(nh) * 2 + ni] =                             \
                    __builtin_amdgcn_mfma_f32_16x16x32_bf16(                    \
                        a0[mi], b0[ni], acc[(mh) * 4 + mi][(nh) * 2 + ni], 0, 0, 0); \
                acc[(mh) * 4 + mi][(nh) * 2 + ni] =                             \
                    __builtin_amdgcn_mfma_f32_16x16x32_bf16(                    \
                        a1[mi], b1[ni], acc[(mh) * 4 + mi][(nh) * 2 + ni], 0, 0, 0); \
            }                                                                   \
        __builtin_amdgcn_s_setprio(0);                                          \
        WAITC                                                                   \
        asm volatile("s_barrier" ::: "memory");                                 \
    } while (0)

    // ---- prologue: tile 0 fully + tile 1 halves {A0,B0}; allow newest 2 stages in flight
    STAGE_A(0, 0, 0); STAGE_B(0, 0, 0); STAGE_B(0, 1, 0); STAGE_A(0, 1, 0);
    STAGE_A(1, 0, 1); STAGE_B(1, 0, 1);
    asm volatile("s_waitcnt vmcnt(4)" ::: "memory");
    asm volatile("s_barrier" ::: "memory");

    // ---- main loop: 2 K-tiles per iteration, 8 phases ----
    for (int j = 0; j < 32; ++j) {
        int t1 = 2 * j + 1;
        PHASE(0, 0, 0, { STAGE_B(1, 1, t1); STAGE_A(1, 1, t1); }, );
        PHASE(0, 0, 1, , );
        PHASE(0, 1, 0, { STAGE_A(0, 0, t1 + 1); }, );
        PHASE(0, 1, 1, { STAGE_B(0, 0, t1 + 1); },
              asm volatile("s_waitcnt vmcnt(4)" ::: "memory"); );
        PHASE(1, 0, 0, { STAGE_B(0, 1, t1 + 1); }, );
        PHASE(1, 0, 1, { STAGE_A(0, 1, t1 + 1); }, );
        PHASE(1, 1, 0, { STAGE_A(1, 0, t1 + 2); }, );
        PHASE(1, 1, 1, { STAGE_B(1, 0, t1 + 2); },
              asm volatile("s_waitcnt vmcnt(4)" ::: "memory"); );
    }

    // ---- epilogue: D layout col = lane&15, row = (lane>>4)*4 + reg ----
#pragma unroll
    for (int bi = 0; bi < 4; ++bi) {
        int col = (int)nrow0 + wc * 64 + (bi >> 1) * 32 + (bi & 1) * 16 + lr;
        float bv = bias[col];
#pragma unroll
        for (int ai = 0; ai < 8; ++ai) {
            int row0 = (int)mrow0 + wr * 128 + (ai >> 2) * 64 + (ai & 3) * 16 + hi * 4;
            f32x4 v = acc[ai][bi];
#pragma unroll
            for (int r = 0; r < 4; ++r)
                C[(size_t)(row0 + r) * Oq + col] = v[r] + bv;
        }
    }
#undef STAGE_A
#undef STAGE_B
#undef PHASE
}

// ---------------- routing + LoRA (adds into C) ----------------
__global__ __launch_bounds__(256) void route_lora(
    const float* __restrict__ x,    // [B][S][D]
    const float* __restrict__ A,    // [E][R][D]
    const float* __restrict__ Bm,   // [E][O][R]
    const float* __restrict__ Wr,   // [E][D]
    const float* __restrict__ br,   // [E]
    float* __restrict__ out) {
    int token = blockIdx.x;              // 0 .. B*IMG_LEN-1
    int bb = token / IMG_LEN, si = token - bb * IMG_LEN;
    int s = IMG_START + si;
    const float* xrow = x + ((size_t)bb * Sq + s) * Dq;

    __shared__ __align__(16) float xs[Dq];
    __shared__ double lg[Eq];
    __shared__ float tv[Rq];
    __shared__ int esel;

    int tid = threadIdx.x, lane = tid & 63, wid = tid >> 6;

    for (int i = tid; i < Dq / 4; i += 256)
        ((float4*)xs)[i] = ((const float4*)xrow)[i];
    __syncthreads();

    // logits in fp64 (argmax stability vs reference)
#pragma unroll
    for (int eo = 0; eo < 2; ++eo) {
        int e = wid * 2 + eo;
        const float* wre = Wr + (size_t)e * Dq;
        double sum = 0.0;
        for (int k = lane; k < Dq; k += 64)
            sum += (double)xs[k] * (double)wre[k];
        for (int off = 32; off; off >>= 1) sum += __shfl_xor(sum, off);
        if (lane == 0) lg[e] = sum + (double)br[e];
    }
    __syncthreads();

    if (tid == 0) {
        double mx = lg[0]; int am = 0;
        for (int e = 1; e < Eq; ++e) if (lg[e] > mx) { mx = lg[e]; am = e; }
        double ex[Eq], den = 0.0;
        for (int e = 0; e < Eq; ++e) { ex[e] = exp(lg[e] - mx); den += ex[e]; }
        for (int e = 0; e < Eq; ++e) {
            float rf = (float)(ex[e] / den);
            out[ROUT_OFF + (size_t)token * Eq + e] = rf;
            float oh = (e == am) ? 1.0f : 0.0f;
            out[EC_OFF + (size_t)token * Eq + e] = (oh - rf) + rf;
        }
        esel = am;
    }
    __syncthreads();
    int e = esel;

    // t[r] = dot(x, A[e][r])
#pragma unroll
    for (int ro = 0; ro < 4; ++ro) {
        int r = wid * 4 + ro;
        const float* ar = A + ((size_t)e * Rq + r) * Dq;
        float sum = 0.0f;
        for (int k = lane; k < Dq; k += 64) sum += xs[k] * ar[k];
        for (int off = 32; off; off >>= 1) sum += __shfl_xor(sum, off);
        if (lane == 0) tv[r] = sum;
    }
    __syncthreads();

    // lora[o] = 2 * sum_r t[r] * Bm[e][o][r], RMW into out
    float* orow = out + ((size_t)bb * Sq + s) * Oq;
    for (int o = tid; o < Oq; o += 256) {
        const float4* bp = (const float4*)(Bm + ((size_t)e * Oq + o) * Rq);
        float acc = 0.0f;
#pragma unroll
        for (int j = 0; j < 4; ++j) {
            float4 bv = bp[j];
            acc += bv.x * tv[j * 4 + 0] + bv.y * tv[j * 4 + 1] +
                   bv.z * tv[j * 4 + 2] + bv.w * tv[j * 4 + 3];
        }
        orow[o] += SCALING * acc;
    }
}

// ---------------- launch ----------------
extern "C" void kernel_launch(void* const* d_in, const int* in_sizes, int n_in,
                              void* d_out, int out_size, void* d_ws, size_t ws_size,
                              hipStream_t stream) {
    const float* x  = (const float*)d_in[0];
    const float* W  = (const float*)d_in[1];
    const float* b  = (const float*)d_in[2];
    const float* A  = (const float*)d_in[3];
    const float* Bm = (const float*)d_in[4];
    const float* Wr = (const float*)d_in[5];
    const float* br = (const float*)d_in[6];
    float* out = (float*)d_out;

    unsigned short* xb = (unsigned short*)d_ws;                   // 16384*4096 bf16
    unsigned short* Wb = xb + (size_t)M_TOT * Dq;                 // 4096*4096 bf16

    cvt_kernel<<<2048, 256, 0, stream>>>(x, xb, (long)M_TOT * Dq / 4);
    cvt_kernel<<<1024, 256, 0, stream>>>(W, Wb, (long)Oq * Dq / 4);

    gemm256<<<(M_TOT / 256) * (Oq / 256), 512, 0, stream>>>(xb, Wb, b, out);

    route_lora<<<Bq * IMG_LEN, 256, 0, stream>>>(x, A, Bm, Wr, br, out);
}

// Round 3
// 1593.815 us; speedup vs baseline: 1.0887x; 1.0418x over previous
//
#include <hip/hip_runtime.h>
#include <cstdint>
#include <cstddef>

// ---------------- constants ----------------
#define Bq 8
#define Sq 2048
#define Dq 4096
#define Oq 4096
#define Eq 8
#define Rq 16
#define IMG_START 34
#define IMG_LEN 576
#define SCALING 2.0f

#define M_TOT (Bq * Sq)                         // 16384
#define FINAL_N ((size_t)M_TOT * Oq)            // 67108864
#define ROUT_OFF FINAL_N
#define EC_OFF (FINAL_N + (size_t)Bq * IMG_LEN * Eq)

#define NT 64                                   // K tiles of 64 (K = 4096)

typedef short bf16x8 __attribute__((ext_vector_type(8)));
typedef float f32x4 __attribute__((ext_vector_type(4)));

// ---------------- helpers ----------------
__device__ __forceinline__ unsigned short f2bf(float f) {
    unsigned int u = __float_as_uint(f);
    unsigned int lsb = (u >> 16) & 1u;
    u += 0x7fffu + lsb;           // round-to-nearest-even
    return (unsigned short)(u >> 16);
}

__device__ __forceinline__ void gload16(const void* g, void* l) {
    __builtin_amdgcn_global_load_lds(
        (const __attribute__((address_space(1))) void*)g,
        (__attribute__((address_space(3))) void*)l, 16, 0, 0);
}

// ---------------- fp32 -> bf16 convert ----------------
__global__ __launch_bounds__(256) void cvt_kernel(const float* __restrict__ in,
                                                  unsigned short* __restrict__ out,
                                                  long n4) {
    long i = (long)blockIdx.x * blockDim.x + threadIdx.x;
    long stride = (long)gridDim.x * blockDim.x;
    typedef unsigned short us4 __attribute__((ext_vector_type(4)));
    for (long v = i; v < n4; v += stride) {
        float4 f = ((const float4*)in)[v];
        us4 o;
        o.x = f2bf(f.x); o.y = f2bf(f.y); o.z = f2bf(f.z); o.w = f2bf(f.w);
        ((us4*)out)[v] = o;
    }
}

// ---------------- bf16 GEMM, 256x256 tile, 8-phase counted-vmcnt ----------------
// C[m][n] = sum_k A[m][k] * Bt[n][k] + bias[n]
// 8 waves (2M x 4N), per-wave output 128x64. LDS 128 KiB.
// Register-cached fragments: A-half read once per 2 phases, B-halves once per
// K-tile -> 48 ds_read_b128 / 2-tile iter (was 96, LDS-bound at MfmaUtil 36%).
// vmcnt(4) at end of phases 4 and 8 only; never vmcnt(0) in main loop.

__global__ __launch_bounds__(512, 2) void gemm256(
    const unsigned short* __restrict__ Ag,   // [M][K] bf16
    const unsigned short* __restrict__ Bg,   // [N][K] bf16
    const float* __restrict__ bias,          // [N]
    float* __restrict__ C) {                 // [M][N] fp32
    __shared__ __align__(16) unsigned short ldsA[2][2][8192];
    __shared__ __align__(16) unsigned short ldsB[2][2][8192];

    const int tid = threadIdx.x;
    const int lane = tid & 63, wid = tid >> 6;
    const int wr = wid >> 2, wc = wid & 3;
    const int lr = lane & 15, hi = lane >> 4, l7 = lane & 7;

    // XCD-aware swizzle: nwg = 64*16 = 1024, %8 == 0 -> simple bijective form
    int bid = blockIdx.x;
    int swz = (bid & 7) * 128 + (bid >> 3);
    int tm = swz >> 4, tn = swz & 15;
    const size_t mrow0 = (size_t)tm * 256, nrow0 = (size_t)tn * 256;

    // ---- staging constants (per-thread) ----
    const int q0 = tid, q1 = 512 + tid;
    const int r0 = q0 >> 3, c0 = (q0 & 7) ^ (r0 & 7);
    const int r1 = q1 >> 3, c1 = (q1 & 7) ^ (r1 & 7);
    const size_t garow0 = (mrow0 + (size_t)((r0 >> 6) << 7) + (r0 & 63)) * Dq + c0 * 8;
    const size_t garow1 = (mrow0 + (size_t)((r1 >> 6) << 7) + (r1 & 63)) * Dq + c1 * 8;
    const size_t gbrow0 = (nrow0 + (size_t)((r0 >> 5) << 6) + (r0 & 31)) * Dq + c0 * 8;
    const size_t gbrow1 = (nrow0 + (size_t)((r1 >> 5) << 6) + (r1 & 31)) * Dq + c1 * 8;
    const int ldst0 = (0 * 512 + (wid << 6)) * 8;   // ushort index
    const int ldst1 = (1 * 512 + (wid << 6)) * 8;

    // ---- ds_read constants ----
    const int sl0 = (hi ^ l7) * 8;          // kk=0..31 slot (ushort idx)
    const int sl1 = ((4 + hi) ^ l7) * 8;    // kk=32..63 slot
    const int arow = wr * 4096 + lr * 64;   // + mi*1024
    const int brow = wc * 2048 + lr * 64;   // + ni*1024

    f32x4 acc[8][4] = {};
    bf16x8 a0[4], a1[4];       // current A-half fragments (k-slice 0 / 1)
    bf16x8 p0[2], p1[2];       // B-half 0 fragments
    bf16x8 q0v[2], q1v[2];     // B-half 1 fragments

#define STAGE_A(bf, mh, tile) do {                                              \
        int kt_ = ((tile) < NT ? (tile) : NT - 1) * 64;                         \
        gload16(Ag + garow0 + (size_t)(mh) * 64 * Dq + kt_, &ldsA[bf][mh][ldst0]); \
        gload16(Ag + garow1 + (size_t)(mh) * 64 * Dq + kt_, &ldsA[bf][mh][ldst1]); \
    } while (0)
#define STAGE_B(bf, nh, tile) do {                                              \
        int kt_ = ((tile) < NT ? (tile) : NT - 1) * 64;                         \
        gload16(Bg + gbrow0 + (size_t)(nh) * 32 * Dq + kt_, &ldsB[bf][nh][ldst0]); \
        gload16(Bg + gbrow1 + (size_t)(nh) * 32 * Dq + kt_, &ldsB[bf][nh][ldst1]); \
    } while (0)

#define RD_A(bf, mh)                                                            \
    _Pragma("unroll") for (int mi = 0; mi < 4; ++mi) {                          \
        a0[mi] = *(const bf16x8*)&ldsA[bf][mh][arow + mi * 1024 + sl0];         \
        a1[mi] = *(const bf16x8*)&ldsA[bf][mh][arow + mi * 1024 + sl1];         \
    }
#define RD_B0(bf)                                                               \
    _Pragma("unroll") for (int ni = 0; ni < 2; ++ni) {                          \
        p0[ni] = *(const bf16x8*)&ldsB[bf][0][brow + ni * 1024 + sl0];          \
        p1[ni] = *(const bf16x8*)&ldsB[bf][0][brow + ni * 1024 + sl1];          \
    }
#define RD_B1(bf)                                                               \
    _Pragma("unroll") for (int ni = 0; ni < 2; ++ni) {                          \
        q0v[ni] = *(const bf16x8*)&ldsB[bf][1][brow + ni * 1024 + sl0];         \
        q1v[ni] = *(const bf16x8*)&ldsB[bf][1][brow + ni * 1024 + sl1];         \
    }
#define MM(mh, nh, B0a, B1a)                                                    \
    _Pragma("unroll") for (int mi = 0; mi < 4; ++mi)                            \
    _Pragma("unroll") for (int ni = 0; ni < 2; ++ni) {                          \
        acc[(mh) * 4 + mi][(nh) * 2 + ni] =                                     \
            __builtin_amdgcn_mfma_f32_16x16x32_bf16(                            \
                a0[mi], B0a[ni], acc[(mh) * 4 + mi][(nh) * 2 + ni], 0, 0, 0);   \
        acc[(mh) * 4 + mi][(nh) * 2 + ni] =                                     \
            __builtin_amdgcn_mfma_f32_16x16x32_bf16(                            \
                a1[mi], B1a[ni], acc[(mh) * 4 + mi][(nh) * 2 + ni], 0, 0, 0);   \
    }

#define PH(READS, STAGES, MFMAS, WAITC) do {                                    \
        READS                                                                   \
        STAGES                                                                  \
        asm volatile("s_barrier" ::: "memory");                                 \
        asm volatile("s_waitcnt lgkmcnt(0)" ::: "memory");                      \
        __builtin_amdgcn_sched_barrier(0);                                      \
        __builtin_amdgcn_s_setprio(1);                                          \
        MFMAS                                                                   \
        __builtin_amdgcn_s_setprio(0);                                          \
        WAITC                                                                   \
        asm volatile("s_barrier" ::: "memory");                                 \
    } while (0)

    // ---- prologue: tile 0 fully + tile 1 halves {A0,B0} ----
    STAGE_A(0, 0, 0); STAGE_B(0, 0, 0); STAGE_B(0, 1, 0); STAGE_A(0, 1, 0);
    STAGE_A(1, 0, 1); STAGE_B(1, 0, 1);
    asm volatile("s_waitcnt vmcnt(4)" ::: "memory");
    asm volatile("s_barrier" ::: "memory");

    // ---- main loop: 2 K-tiles per iteration, 8 phases ----
    // Staging/wait schedule identical to verified round-2 kernel; only the
    // ds_read pattern changed (register-cached fragments).
    for (int j = 0; j < 32; ++j) {
        int t1 = 2 * j + 1;
        PH(RD_A(0, 0) RD_B0(0),
           { STAGE_B(1, 1, t1); STAGE_A(1, 1, t1);
             asm volatile("s_waitcnt lgkmcnt(8)" ::: "memory"); },
           MM(0, 0, p0, p1), );
        PH(RD_B1(0), , MM(0, 1, q0v, q1v), );
        PH(RD_A(0, 1), { STAGE_A(0, 0, t1 + 1); }, MM(1, 0, p0, p1), );
        PH(, { STAGE_B(0, 0, t1 + 1); }, MM(1, 1, q0v, q1v),
           asm volatile("s_waitcnt vmcnt(4)" ::: "memory"); );
        PH(RD_A(1, 0) RD_B0(1),
           { STAGE_B(0, 1, t1 + 1);
             asm volatile("s_waitcnt lgkmcnt(8)" ::: "memory"); },
           MM(0, 0, p0, p1), );
        PH(RD_B1(1), { STAGE_A(0, 1, t1 + 1); }, MM(0, 1, q0v, q1v), );
        PH(RD_A(1, 1), { STAGE_A(1, 0, t1 + 2); }, MM(1, 0, p0, p1), );
        PH(, { STAGE_B(1, 0, t1 + 2); }, MM(1, 1, q0v, q1v),
           asm volatile("s_waitcnt vmcnt(4)" ::: "memory"); );
    }

    // ---- epilogue: D layout col = lane&15, row = (lane>>4)*4 + reg ----
#pragma unroll
    for (int bi = 0; bi < 4; ++bi) {
        int col = (int)nrow0 + wc * 64 + (bi >> 1) * 32 + (bi & 1) * 16 + lr;
        float bv = bias[col];
#pragma unroll
        for (int ai = 0; ai < 8; ++ai) {
            int row0 = (int)mrow0 + wr * 128 + (ai >> 2) * 64 + (ai & 3) * 16 + hi * 4;
            f32x4 v = acc[ai][bi];
#pragma unroll
            for (int r = 0; r < 4; ++r)
                C[(size_t)(row0 + r) * Oq + col] = v[r] + bv;
        }
    }
#undef STAGE_A
#undef STAGE_B
#undef RD_A
#undef RD_B0
#undef RD_B1
#undef MM
#undef PH
}

// ---------------- routing + LoRA (adds into C) ----------------
__global__ __launch_bounds__(256) void route_lora(
    const float* __restrict__ x,    // [B][S][D]
    const float* __restrict__ A,    // [E][R][D]
    const float* __restrict__ Bm,   // [E][O][R]
    const float* __restrict__ Wr,   // [E][D]
    const float* __restrict__ br,   // [E]
    float* __restrict__ out) {
    int token = blockIdx.x;              // 0 .. B*IMG_LEN-1
    int bb = token / IMG_LEN, si = token - bb * IMG_LEN;
    int s = IMG_START + si;
    const float* xrow = x + ((size_t)bb * Sq + s) * Dq;

    __shared__ __align__(16) float xs[Dq];
    __shared__ double lg[Eq];
    __shared__ float tv[Rq];
    __shared__ int esel;

    int tid = threadIdx.x, lane = tid & 63, wid = tid >> 6;

    for (int i = tid; i < Dq / 4; i += 256)
        ((float4*)xs)[i] = ((const float4*)xrow)[i];
    __syncthreads();

    // logits in fp64 (argmax stability vs reference)
#pragma unroll
    for (int eo = 0; eo < 2; ++eo) {
        int e = wid * 2 + eo;
        const float* wre = Wr + (size_t)e * Dq;
        double sum = 0.0;
        for (int k = lane; k < Dq; k += 64)
            sum += (double)xs[k] * (double)wre[k];
        for (int off = 32; off; off >>= 1) sum += __shfl_xor(sum, off);
        if (lane == 0) lg[e] = sum + (double)br[e];
    }
    __syncthreads();

    if (tid == 0) {
        double mx = lg[0]; int am = 0;
        for (int e = 1; e < Eq; ++e) if (lg[e] > mx) { mx = lg[e]; am = e; }
        double ex[Eq], den = 0.0;
        for (int e = 0; e < Eq; ++e) { ex[e] = exp(lg[e] - mx); den += ex[e]; }
        for (int e = 0; e < Eq; ++e) {
            float rf = (float)(ex[e] / den);
            out[ROUT_OFF + (size_t)token * Eq + e] = rf;
            float oh = (e == am) ? 1.0f : 0.0f;
            out[EC_OFF + (size_t)token * Eq + e] = (oh - rf) + rf;
        }
        esel = am;
    }
    __syncthreads();
    int e = esel;

    // t[r] = dot(x, A[e][r])
#pragma unroll
    for (int ro = 0; ro < 4; ++ro) {
        int r = wid * 4 + ro;
        const float* ar = A + ((size_t)e * Rq + r) * Dq;
        float sum = 0.0f;
        for (int k = lane; k < Dq; k += 64) sum += xs[k] * ar[k];
        for (int off = 32; off; off >>= 1) sum += __shfl_xor(sum, off);
        if (lane == 0) tv[r] = sum;
    }
    __syncthreads();

    // lora[o] = 2 * sum_r t[r] * Bm[e][o][r], RMW into out
    float* orow = out + ((size_t)bb * Sq + s) * Oq;
    for (int o = tid; o < Oq; o += 256) {
        const float4* bp = (const float4*)(Bm + ((size_t)e * Oq + o) * Rq);
        float acc = 0.0f;
#pragma unroll
        for (int j = 0; j < 4; ++j) {
            float4 bv = bp[j];
            acc += bv.x * tv[j * 4 + 0] + bv.y * tv[j * 4 + 1] +
                   bv.z * tv[j * 4 + 2] + bv.w * tv[j * 4 + 3];
        }
        orow[o] += SCALING * acc;
    }
}

// ---------------- launch ----------------
extern "C" void kernel_launch(void* const* d_in, const int* in_sizes, int n_in,
                              void* d_out, int out_size, void* d_ws, size_t ws_size,
                              hipStream_t stream) {
    const float* x  = (const float*)d_in[0];
    const float* W  = (const float*)d_in[1];
    const float* b  = (const float*)d_in[2];
    const float* A  = (const float*)d_in[3];
    const float* Bm = (const float*)d_in[4];
    const float* Wr = (const float*)d_in[5];
    const float* br = (const float*)d_in[6];
    float* out = (float*)d_out;

    unsigned short* xb = (unsigned short*)d_ws;                   // 16384*4096 bf16
    unsigned short* Wb = xb + (size_t)M_TOT * Dq;                 // 4096*4096 bf16

    cvt_kernel<<<2048, 256, 0, stream>>>(x, xb, (long)M_TOT * Dq / 4);
    cvt_kernel<<<1024, 256, 0, stream>>>(W, Wb, (long)Oq * Dq / 4);

    gemm256<<<(M_TOT / 256) * (Oq / 256), 512, 0, stream>>>(xb, Wb, b, out);

    route_lora<<<Bq * IMG_LEN, 256, 0, stream>>>(x, A, Bm, Wr, br, out);
}